// Round 6
// baseline (1766.392 us; speedup 1.0000x reference)
//
#include <hip/hip_runtime.h>
#include <math.h>

#define BB 16
#define TT 4096
#define EE 1024
#define HALF 2048
#define WIN 15
#define EPSF 1e-6f
#define PI_F   3.14159265358979323846f
#define PIO2_F 1.57079632679489662f
#define REP 16   // diagnostic amplification: idempotent repeat inside each kernel

// Branchless cephes-style asin: ~16 VALU ops, 1 sqrt, no divergence.
__device__ __forceinline__ float fast_asinf(float v) {
    float a  = fabsf(v);
    float z1 = a * a;
    float z2 = 0.5f * (1.0f - a);
    bool big = a > 0.5f;
    float z = big ? z2 : z1;
    float s = big ? sqrtf(z) : a;
    float p = fmaf(z, 4.2163199048e-2f, 2.4181311049e-2f);
    p = fmaf(z, p, 4.5470025998e-2f);
    p = fmaf(z, p, 7.4953002686e-2f);
    p = fmaf(z, p, 1.6666752422e-1f);
    float r = fmaf(s * z, p, s);
    float rb = fmaf(-2.0f, r, PIO2_F);
    r = big ? rb : r;
    return copysignf(r, v);
}

// ---------------------------------------------------------------------------
// Phase kernel (R2/R5 structure): wave per row. REP-amplified.
// ---------------------------------------------------------------------------
__global__ void phase_kernel(const float* __restrict__ x,
                             const float* __restrict__ taper,
                             float* __restrict__ phases_T,
                             float* __restrict__ c0_T) {
    #pragma unroll 1
    for (int rep = 0; rep < REP; ++rep) {
        const int wave = threadIdx.x >> 6;
        const int lane = threadIdx.x & 63;
        const int row  = blockIdx.x * 4 + wave;
        const int b = row >> 12;
        const int t = row & (TT - 1);
        const float tap = taper[t];
        const float* xr = x + (size_t)row * EE;

        const float c0 = xr[0] * tap;
        const float r = fabsf(c0) + EPSF;
        const float scale = tap / r;
        const float start = (c0 >= 0.0f) ? 0.0f : PI_F;
        const float LO = -1.0f + EPSF, HI = 1.0f - EPSF;

        const float4* xr4 = (const float4*)xr;
        float sum = 0.0f;
        #pragma unroll
        for (int j = 0; j < 4; ++j) {
            float4 v = xr4[j * 64 + lane];
            float a0 = fast_asinf(fminf(fmaxf(v.x * scale, LO), HI));
            if ((j | lane) == 0) a0 = 0.0f;
            sum += a0;
            sum += fast_asinf(fminf(fmaxf(v.y * scale, LO), HI));
            sum += fast_asinf(fminf(fmaxf(v.z * scale, LO), HI));
            sum += fast_asinf(fminf(fmaxf(v.w * scale, LO), HI));
        }
        #pragma unroll
        for (int off = 32; off > 0; off >>= 1)
            sum += __shfl_xor(sum, off, 64);

        if (lane == 0) {
            phases_T[t * BB + b] = start + sum;
            c0_T[t * BB + b]     = c0;
        }
    }
}

// ---------------------------------------------------------------------------
// tdiff: causal triangular moving average (window 15). REP-amplified.
// ---------------------------------------------------------------------------
__global__ void tdiff_kernel(const float* __restrict__ c0_T,
                             float* __restrict__ tdiff_T) {
    #pragma unroll 1
    for (int rep = 0; rep < REP; ++rep) {
        const int f = blockIdx.x * blockDim.x + threadIdx.x;
        if (f < BB * TT) {
            const int t = f >> 4;
            const int b = f & 15;
            float num = 0.0f;
            #pragma unroll
            for (int d = 1; d <= WIN; ++d) {
                if (d <= t) num += (float)d * c0_T[(t - d) * BB + b];
            }
            const int s = (t < WIN) ? t : WIN;
            const float norm = 0.5f * (float)s * (float)(s + 1);
            tdiff_T[f] = (norm > 0.0f) ? (num / norm) : 0.0f;
        }
    }
}

// ---------------------------------------------------------------------------
// GEMM (R5 structure): global_load_lds double-buffered weight stream.
// REP-amplified (accumulators and stage pipeline reset per rep).
// ---------------------------------------------------------------------------
__device__ __forceinline__ void gld_lds16(const float* g, float* l) {
    __builtin_amdgcn_global_load_lds(
        (const __attribute__((address_space(1))) unsigned int*)g,
        (__attribute__((address_space(3))) unsigned int*)l,
        16, 0, 0);
}

template <int K, int MODE>
__global__ void __launch_bounds__(256)
gemm_kernel(const float* __restrict__ A0, const float* __restrict__ W0,
            const float* __restrict__ bias0, float* __restrict__ out0,
            const float* __restrict__ A1, const float* __restrict__ W1,
            const float* __restrict__ bias1, float* __restrict__ out1) {
    const int BK = 256;
    const int NT = K / BK;
    __shared__ float wbuf[2][8 * BK];

    const int nb = HALF / 8;
    const int g = blockIdx.x / nb;
    const int obase = (blockIdx.x % nb) * 8;

    const float* A    = g ? A1 : A0;
    const float* W    = g ? W1 : W0;
    const float* bias = g ? bias1 : bias0;
    float* out        = g ? out1 : out0;

    const int wv   = threadIdx.x >> 6;
    const int lane = threadIdx.x & 63;
    const int c0 = wv * 2, c1 = wv * 2 + 1;
    const float4* A4 = (const float4*)A;

    auto stage = [&](int t, int s) {
        #pragma unroll
        for (int i = 0; i < 2; ++i) {
            const int rr = wv + 4 * i;
            const float* src = W + (size_t)(obase + rr) * K + t * BK + lane * 4;
            float* dst = &wbuf[s][rr * BK];
            gld_lds16(src, dst);
        }
    };

    #pragma unroll 1
    for (int rep = 0; rep < REP; ++rep) {
        float acc0[16], acc1[16];
        #pragma unroll
        for (int i = 0; i < 16; ++i) { acc0[i] = 0.0f; acc1[i] = 0.0f; }

        stage(0, 0);
        __syncthreads();

        int cur = 0;
        for (int t = 0; t < NT; ++t) {
            if (t + 1 < NT) stage(t + 1, cur ^ 1);

            const int kb = t * BK + lane * 4;
            float4 a[4][4];
            #pragma unroll
            for (int j = 0; j < 4; ++j)
                #pragma unroll
                for (int q = 0; q < 4; ++q)
                    a[j][q] = A4[(size_t)(kb + j) * 4 + q];

            float4 w0v = *(const float4*)&wbuf[cur][c0 * BK + lane * 4];
            float4 w1v = *(const float4*)&wbuf[cur][c1 * BK + lane * 4];
            float wA[4] = {w0v.x, w0v.y, w0v.z, w0v.w};
            float wB[4] = {w1v.x, w1v.y, w1v.z, w1v.w};

            #pragma unroll
            for (int j = 0; j < 4; ++j) {
                const float wa = wA[j], wb = wB[j];
                acc0[0]+=wa*a[j][0].x; acc0[1]+=wa*a[j][0].y; acc0[2]+=wa*a[j][0].z; acc0[3]+=wa*a[j][0].w;
                acc0[4]+=wa*a[j][1].x; acc0[5]+=wa*a[j][1].y; acc0[6]+=wa*a[j][1].z; acc0[7]+=wa*a[j][1].w;
                acc0[8]+=wa*a[j][2].x; acc0[9]+=wa*a[j][2].y; acc0[10]+=wa*a[j][2].z; acc0[11]+=wa*a[j][2].w;
                acc0[12]+=wa*a[j][3].x; acc0[13]+=wa*a[j][3].y; acc0[14]+=wa*a[j][3].z; acc0[15]+=wa*a[j][3].w;
                acc1[0]+=wb*a[j][0].x; acc1[1]+=wb*a[j][0].y; acc1[2]+=wb*a[j][0].z; acc1[3]+=wb*a[j][0].w;
                acc1[4]+=wb*a[j][1].x; acc1[5]+=wb*a[j][1].y; acc1[6]+=wb*a[j][1].z; acc1[7]+=wb*a[j][1].w;
                acc1[8]+=wb*a[j][2].x; acc1[9]+=wb*a[j][2].y; acc1[10]+=wb*a[j][2].z; acc1[11]+=wb*a[j][2].w;
                acc1[12]+=wb*a[j][3].x; acc1[13]+=wb*a[j][3].y; acc1[14]+=wb*a[j][3].z; acc1[15]+=wb*a[j][3].w;
            }
            __syncthreads();
            cur ^= 1;
        }

        #pragma unroll
        for (int off = 32; off > 0; off >>= 1) {
            #pragma unroll
            for (int i = 0; i < 16; ++i) {
                acc0[i] += __shfl_xor(acc0[i], off, 64);
                acc1[i] += __shfl_xor(acc1[i], off, 64);
            }
        }

        const bool w0w = (lane == 0), w1w = (lane == 32);
        if (w0w || w1w) {
            const int c = w0w ? c0 : c1;
            const int o = obase + c;
            const float bs = bias[o];
            float v[16];
            #pragma unroll
            for (int i = 0; i < 16; ++i) {
                float s = (w0w ? acc0[i] : acc1[i]) + bs;
                if (MODE == 0) s = s / (1.0f + expf(-s));
                else           s = tanhf(s);
                v[i] = s;
            }
            if (MODE == 0) {
                float4* dst = (float4*)&out[o * BB];
                dst[0] = make_float4(v[0], v[1], v[2], v[3]);
                dst[1] = make_float4(v[4], v[5], v[6], v[7]);
                dst[2] = make_float4(v[8], v[9], v[10], v[11]);
                dst[3] = make_float4(v[12], v[13], v[14], v[15]);
            } else {
                #pragma unroll
                for (int i = 0; i < 16; ++i)
                    out[(size_t)i * (HALF * 2) + o * 2 + g] = v[i];
            }
        }
        __syncthreads();   // keep reps' LDS usage ordered
    }
}

extern "C" void kernel_launch(void* const* d_in, const int* in_sizes, int n_in,
                              void* d_out, int out_size, void* d_ws, size_t ws_size,
                              hipStream_t stream) {
    const float* x     = (const float*)d_in[0];
    const float* taper = (const float*)d_in[1];
    const float* cW1   = (const float*)d_in[2];
    const float* cb1   = (const float*)d_in[3];
    const float* cW2   = (const float*)d_in[4];
    const float* cb2   = (const float*)d_in[5];
    const float* pW1   = (const float*)d_in[6];
    const float* pb1   = (const float*)d_in[7];
    const float* pW2   = (const float*)d_in[8];
    const float* pb2   = (const float*)d_in[9];
    float* out = (float*)d_out;
    float* ws  = (float*)d_ws;

    float* phases_T = ws;
    float* c0_T     = ws + 65536;
    float* tdiff_T  = ws + 131072;
    float* H1_T     = ws + 196608;
    float* H2_T     = ws + 229376;

    phase_kernel<<<BB * TT / 4, 256, 0, stream>>>(x, taper, phases_T, c0_T);
    tdiff_kernel<<<BB * TT / 256, 256, 0, stream>>>(c0_T, tdiff_T);
    gemm_kernel<TT, 0><<<512, 256, 0, stream>>>(phases_T, cW1, cb1, H1_T,
                                                tdiff_T, pW1, pb1, H2_T);
    gemm_kernel<HALF, 1><<<512, 256, 0, stream>>>(H1_T, cW2, cb2, out,
                                                  H2_T, pW2, pb2, out);
}

// Round 7
// 108.506 us; speedup vs baseline: 16.2793x; 16.2793x over previous
//
#include <hip/hip_runtime.h>
#include <math.h>

#define BB 16
#define TT 4096
#define EE 1024
#define HALF 2048
#define WIN 15
#define EPSF 1e-6f
#define PI_F   3.14159265358979323846f
#define PIO2_F 1.57079632679489662f

// Branchless cephes-style asin: ~16 VALU ops, 1 sqrt, no divergence.
__device__ __forceinline__ float fast_asinf(float v) {
    float a  = fabsf(v);
    float z1 = a * a;
    float z2 = 0.5f * (1.0f - a);
    bool big = a > 0.5f;
    float z = big ? z2 : z1;
    float s = big ? sqrtf(z) : a;
    float p = fmaf(z, 4.2163199048e-2f, 2.4181311049e-2f);
    p = fmaf(z, p, 4.5470025998e-2f);
    p = fmaf(z, p, 7.4953002686e-2f);
    p = fmaf(z, p, 1.6666752422e-1f);
    float r = fmaf(s * z, p, s);
    float rb = fmaf(-2.0f, r, PIO2_F);
    r = big ? rb : r;
    return copysignf(r, v);
}

// ---------------------------------------------------------------------------
// Phase kernel: wave per row. Outputs now B-MAJOR: arr[b*TT + t].
// ---------------------------------------------------------------------------
__global__ void phase_kernel(const float* __restrict__ x,
                             const float* __restrict__ taper,
                             float* __restrict__ phases_b,
                             float* __restrict__ c0_b) {
    const int wave = threadIdx.x >> 6;
    const int lane = threadIdx.x & 63;
    const int row  = blockIdx.x * 4 + wave;      // [0, B*T)
    const int b = row >> 12;
    const int t = row & (TT - 1);
    const float tap = taper[t];
    const float* xr = x + (size_t)row * EE;

    const float c0 = xr[0] * tap;
    const float r = fabsf(c0) + EPSF;
    const float scale = tap / r;
    const float start = (c0 >= 0.0f) ? 0.0f : PI_F;
    const float LO = -1.0f + EPSF, HI = 1.0f - EPSF;

    const float4* xr4 = (const float4*)xr;
    float sum = 0.0f;
    #pragma unroll
    for (int j = 0; j < 4; ++j) {
        float4 v = xr4[j * 64 + lane];
        float a0 = fast_asinf(fminf(fmaxf(v.x * scale, LO), HI));
        if ((j | lane) == 0) a0 = 0.0f;          // element 0 excluded
        sum += a0;
        sum += fast_asinf(fminf(fmaxf(v.y * scale, LO), HI));
        sum += fast_asinf(fminf(fmaxf(v.z * scale, LO), HI));
        sum += fast_asinf(fminf(fmaxf(v.w * scale, LO), HI));
    }
    #pragma unroll
    for (int off = 32; off > 0; off >>= 1)
        sum += __shfl_xor(sum, off, 64);

    if (lane == 0) {
        phases_b[b * TT + t] = start + sum;      // 4 consecutive t per block
        c0_b[b * TT + t]     = c0;
    }
}

// ---------------------------------------------------------------------------
// tdiff: causal triangular moving average (window 15), b-major in/out.
// ---------------------------------------------------------------------------
__global__ void tdiff_kernel(const float* __restrict__ c0_b,
                             float* __restrict__ tdiff_b) {
    const int f = blockIdx.x * blockDim.x + threadIdx.x;   // b*TT + t
    if (f >= BB * TT) return;
    const int t = f & (TT - 1);
    float num = 0.0f;
    #pragma unroll
    for (int d = 1; d <= WIN; ++d) {
        if (d <= t) num += (float)d * c0_b[f - d];
    }
    const int s = (t < WIN) ? t : WIN;
    const float norm = 0.5f * (float)s * (float)(s + 1);
    tdiff_b[f] = (norm > 0.0f) ? (num / norm) : 0.0f;
}

// ---------------------------------------------------------------------------
// GEMM (M=16): A is b-major [16][K]. Per block: 8 output cols (2 per wave).
// Per K-tile (KT=1024): stage A-tile [16][KT] into LDS via global_load_lds
// (coalesced, +4-word row pad), stream weights as coalesced float4 into
// registers, contiguous ds_read_b128 for A. No gathers anywhere.
// MODE 0: silu -> H_b[b*HALF + o].  MODE 1: tanh -> out[b*4096 + o*2 + g].
// ---------------------------------------------------------------------------
__device__ __forceinline__ void gld_lds16(const float* g, float* l) {
    __builtin_amdgcn_global_load_lds(
        (const __attribute__((address_space(1))) unsigned int*)g,
        (__attribute__((address_space(3))) unsigned int*)l,
        16, 0, 0);
}

template <int K, int MODE>
__global__ void __launch_bounds__(256)
gemm_kernel(const float* __restrict__ A0, const float* __restrict__ W0,
            const float* __restrict__ bias0, float* __restrict__ out0,
            const float* __restrict__ A1, const float* __restrict__ W1,
            const float* __restrict__ bias1, float* __restrict__ out1) {
    constexpr int KT = 1024;
    constexpr int NT = K / KT;
    constexpr int LROW = KT + 4;                  // 16B-aligned row stride, pad
    __shared__ float als[16 * LROW];              // 65.8 KiB -> 2 blocks/CU

    const int nb = HALF / 8;                      // 256 blocks per problem
    const int g = blockIdx.x / nb;
    const int obase = (blockIdx.x % nb) * 8;

    const float* A    = g ? A1 : A0;
    const float* W    = g ? W1 : W0;
    const float* bias = g ? bias1 : bias0;
    float* out        = g ? out1 : out0;

    const int wv   = threadIdx.x >> 6;            // 0..3
    const int lane = threadIdx.x & 63;
    const int col0 = obase + wv * 2;
    const int col1 = col0 + 1;
    const float* w0p = W + (size_t)col0 * K;
    const float* w1p = W + (size_t)col1 * K;

    float acc0[16], acc1[16];
    #pragma unroll
    for (int i = 0; i < 16; ++i) { acc0[i] = 0.0f; acc1[i] = 0.0f; }

    for (int t = 0; t < NT; ++t) {
        __syncthreads();                          // als free (prev tile done)
        // stage A-tile: wave wv stages rows wv*4..wv*4+3, 4x1KiB per row
        #pragma unroll
        for (int i = 0; i < 4; ++i) {
            const int b = wv * 4 + i;
            const float* src = A + (size_t)b * K + t * KT + lane * 4;
            float* dst = &als[b * LROW];          // uniform base; HW adds lane*16B
            #pragma unroll
            for (int q = 0; q < 4; ++q)
                gld_lds16(src + q * 256, dst + q * 256);
        }
        __syncthreads();                          // drains vmcnt -> tile ready

        // weights for this tile: 8 independent coalesced float4 loads
        float4 w0[4], w1[4];
        #pragma unroll
        for (int s = 0; s < 4; ++s) {
            w0[s] = *(const float4*)(w0p + t * KT + s * 256 + lane * 4);
            w1[s] = *(const float4*)(w1p + t * KT + s * 256 + lane * 4);
        }

        #pragma unroll
        for (int s = 0; s < 4; ++s) {
            #pragma unroll
            for (int b = 0; b < 16; ++b) {
                const float4 a4 = *(const float4*)&als[b * LROW + s * 256 + lane * 4];
                acc0[b] += w0[s].x*a4.x + w0[s].y*a4.y + w0[s].z*a4.z + w0[s].w*a4.w;
                acc1[b] += w1[s].x*a4.x + w1[s].y*a4.y + w1[s].z*a4.z + w1[s].w*a4.w;
            }
        }
    }

    // full-wave butterfly: every lane ends with complete sums
    #pragma unroll
    for (int off = 32; off > 0; off >>= 1) {
        #pragma unroll
        for (int i = 0; i < 16; ++i) {
            acc0[i] += __shfl_xor(acc0[i], off, 64);
            acc1[i] += __shfl_xor(acc1[i], off, 64);
        }
    }

    const bool isw0 = (lane == 0), isw1 = (lane == 32);
    if (isw0 || isw1) {
        const int o = isw0 ? col0 : col1;
        const float bs = bias[o];
        #pragma unroll
        for (int i = 0; i < 16; ++i) {
            float s = (isw0 ? acc0[i] : acc1[i]) + bs;
            if (MODE == 0) {
                s = s / (1.0f + expf(-s));        // silu
                out[(size_t)i * HALF + o] = s;    // H b-major [16][HALF]
            } else {
                s = tanhf(s);
                out[(size_t)i * (HALF * 2) + o * 2 + g] = s;
            }
        }
    }
}

extern "C" void kernel_launch(void* const* d_in, const int* in_sizes, int n_in,
                              void* d_out, int out_size, void* d_ws, size_t ws_size,
                              hipStream_t stream) {
    const float* x     = (const float*)d_in[0];
    const float* taper = (const float*)d_in[1];
    const float* cW1   = (const float*)d_in[2];
    const float* cb1   = (const float*)d_in[3];
    const float* cW2   = (const float*)d_in[4];
    const float* cb2   = (const float*)d_in[5];
    const float* pW1   = (const float*)d_in[6];
    const float* pb1   = (const float*)d_in[7];
    const float* pW2   = (const float*)d_in[8];
    const float* pb2   = (const float*)d_in[9];
    float* out = (float*)d_out;
    float* ws  = (float*)d_ws;

    float* phases_b = ws;                         // [16][4096]
    float* c0_b     = ws + 65536;                 // [16][4096]
    float* tdiff_b  = ws + 131072;                // [16][4096]
    float* H1_b     = ws + 196608;                // [16][2048]
    float* H2_b     = ws + 229376;                // [16][2048]

    phase_kernel<<<BB * TT / 4, 256, 0, stream>>>(x, taper, phases_b, c0_b);
    tdiff_kernel<<<BB * TT / 256, 256, 0, stream>>>(c0_b, tdiff_b);
    gemm_kernel<TT, 0><<<512, 256, 0, stream>>>(phases_b, cW1, cb1, H1_b,
                                                tdiff_b, pW1, pb1, H2_b);
    gemm_kernel<HALF, 1><<<512, 256, 0, stream>>>(H1_b, cW2, cb2, out,
                                                  H2_b, pW2, pb2, out);
}